// Round 13
// baseline (49.702 us; speedup 1.0000x reference)
//
#include <hip/hip_runtime.h>
#include <math.h>

// Problem constants: z [4,32,32,32] f32, embedding [32768,32] f32.
constexpr int Bc   = 4;
constexpr int Dc   = 32;
constexpr int HWc  = 1024;
constexpr int NE   = 32768;
constexpr int POS  = Bc * HWc;        // 4096 positions

constexpr int CCODES = 256;           // codes per block chunk (32 KB in LDS)
constexpr int NCHUNK = NE / CCODES;   // 128
constexpr int PPB    = 128;           // positions per block (2 tiles x 4 waves)
constexpr int NPBLK  = POS / PPB;     // 32

typedef _Float16 f16x8 __attribute__((ext_vector_type(8)));
typedef float    f32x4 __attribute__((ext_vector_type(4)));
typedef unsigned long long u64;

// Monotonic float->uint encoding; pack with ~idx so that among equal values
// the SMALLER index wins under max (== jnp.argmax first-index rule).
__device__ inline u64 packVI(float v, int idx) {
    unsigned u = __float_as_uint(v);
    u = (u & 0x80000000u) ? ~u : (u | 0x80000000u);
    return ((u64)u << 32) | (unsigned)(~idx);
}

// Prep: split-fp16 conversion. Blocks 0..127: embedding -> Es [32768][64]
// (hi dims 0..31, lo dims 32..63; hi+lo = x to ~2^-22). Blocks 128..143:
// z -> Zs [4096][64] same layout (A-frags become plain 16B loads), and zero
// best[]. Keeps ~230 VALU ops/wave out of the hot kernel (r12 lesson: fusing
// the convert into the main kernel bought nothing and cost registers).
__global__ __launch_bounds__(256) void vq_eprep(
    const float* __restrict__ emb, const float* __restrict__ z,
    _Float16* __restrict__ Es, _Float16* __restrict__ Zs,
    u64* __restrict__ best)
{
    float x[Dc];
    _Float16* dptr;
    if (blockIdx.x < NE / 256) {
        const int c = blockIdx.x * 256 + threadIdx.x;       // 0..32767
        const float4* src = reinterpret_cast<const float4*>(emb + (size_t)c * Dc);
#pragma unroll
        for (int q = 0; q < 8; ++q) {
            const float4 v = src[q];
            x[4*q+0] = v.x; x[4*q+1] = v.y; x[4*q+2] = v.z; x[4*q+3] = v.w;
        }
        dptr = Es + (size_t)c * 64;
    } else {
        const int p = (blockIdx.x - NE / 256) * 256 + threadIdx.x;  // 0..4095
        best[p] = 0ULL;            // encoded minimum: any real value wins
        const int b = p >> 10, hw = p & (HWc - 1);
        const float* zp = z + (size_t)b * Dc * HWc + hw;
#pragma unroll
        for (int d = 0; d < Dc; ++d) x[d] = zp[(size_t)d * HWc];
        dptr = Zs + (size_t)p * 64;
    }
    f16x8* dst = reinterpret_cast<f16x8*>(dptr);
#pragma unroll
    for (int q = 0; q < 4; ++q) {
        f16x8 h, l;
#pragma unroll
        for (int r = 0; r < 8; ++r) {
            const float xv = x[8*q+r];
            const _Float16 hv = (_Float16)xv;
            h[r] = hv;
            l[r] = (_Float16)(xv - (float)hv);
        }
        dst[q]     = h;   // hi block
        dst[4 + q] = l;   // lo block
    }
}

// Main: validated split-fp16 MFMA scan (hi*hi + hi*lo + lo*hi; absmax 0 since
// round 8). Round-13: register diet for occupancy. r10-r12 all allocated
// ~200 VGPR (512-reg pool -> 2 waves/SIMD, 30% occ, pipes can't overlap;
// launch_bounds cap was NOT honored). Halve per-wave state: 2 pos-tiles
// (A=16, bval/bct=16, <=4 acc quads), hand-pipelined unroll-1 loop with ONE
// explicit B-prefetch pair, sequential tail. Target <=128 live regs -> 4-5
// waves/SIMD. LDS exactly 32 KB -> 5 blocks/CU. Staging/read swizzle
// identical to r10 (measured 0 conflicts).
__global__ __launch_bounds__(256, 4) void vq_mfma(
    const _Float16* __restrict__ Zs, const _Float16* __restrict__ Es,
    u64* __restrict__ best)
{
    __shared__ __align__(16) char lds[CCODES * 128];   // 32 KB, reused by tail

    const int lin  = blockIdx.x;               // 0..4095
    const int xcd  = lin & 7;                  // dispatch round-robins XCDs
    const int j    = lin >> 3;                 // 0..511
    const int chunk = xcd * (NCHUNK / 8) + (j & (NCHUNK / 8 - 1));
    const int pblk  = j >> 4;                  // 0..31
    const int tid  = threadIdx.x;
    const int wave = tid >> 6, lane = tid & 63;
    const int m = lane & 15, g = lane >> 4;

    // ---- stage chunk -> LDS via global_load_lds, source pre-swizzled ----
    {
        const char* src = (const char*)(Es + (size_t)chunk * CCODES * 64);
        char* dstbase = lds + wave * 1024;           // wave-uniform base
#pragma unroll
        for (int r = 0; r < 8; ++r) {
            const int o    = r * 256 + tid;          // 16B-chunk index
            const int row  = o >> 3;                 // code row 0..255
            const int ccol = o & 7;                  // 16B col 0..7
            const int soff = row * 128 + ((ccol ^ (row & 7)) << 4);
            __builtin_amdgcn_global_load_lds(
                (const __attribute__((address_space(1))) void*)(src + soff),
                (__attribute__((address_space(3))) void*)(dstbase + r * 4096),
                16, 0, 0);
        }
    }

    // ---- A fragments: 2 pos-tiles, plain 16B loads from preconverted Zs ----
    const int posBase0 = pblk * PPB;
    const int posBase  = posBase0 + wave * 32;
    f16x8 Ahi[2], Alo[2];
#pragma unroll
    for (int t = 0; t < 2; ++t) {
        const _Float16* zrow = Zs + (size_t)(posBase + t * 16 + m) * 64 + 8 * g;
        Ahi[t] = *reinterpret_cast<const f16x8*>(zrow);
        Alo[t] = *reinterpret_cast<const f16x8*>(zrow + 32);
    }
#pragma unroll
    for (int t = 0; t < 2; ++t) asm volatile("" : "+v"(Ahi[t]), "+v"(Alo[t]));

    f32x4 zacc = {0.f, 0.f, 0.f, 0.f};
    asm volatile("" : "+v"(zacc));     // persistent zero C-operand quad

    float bval[8];
    int   bct[8];
#pragma unroll
    for (int i = 0; i < 8; ++i) { bval[i] = -INFINITY; bct[i] = 0; }

    __syncthreads();   // staging complete

    // ---- hot loop: 16 code-tiles, one B-pair prefetch ahead ----
    const char* lbase = lds;
    const int off_h = m * 128 + (( g      ^ (m & 7)) << 4);
    const int off_l = m * 128 + (((g + 4) ^ (m & 7)) << 4);

    f16x8 Bh = *reinterpret_cast<const f16x8*>(lbase + off_h);
    f16x8 Bl = *reinterpret_cast<const f16x8*>(lbase + off_l);

#pragma unroll 1
    for (int ct = 0; ct < CCODES / 16; ++ct) {
        const int noff = (ct < CCODES / 16 - 1) ? (ct + 1) * 2048 : 0;
        const f16x8 BhN = *reinterpret_cast<const f16x8*>(lbase + off_h + noff);
        const f16x8 BlN = *reinterpret_cast<const f16x8*>(lbase + off_l + noff);

#pragma unroll
        for (int t = 0; t < 2; ++t) {
            f32x4 acc;
            acc = __builtin_amdgcn_mfma_f32_16x16x32_f16(Ahi[t], Bh, zacc, 0, 0, 0);
            acc = __builtin_amdgcn_mfma_f32_16x16x32_f16(Ahi[t], Bl, acc,  0, 0, 0);
            acc = __builtin_amdgcn_mfma_f32_16x16x32_f16(Alo[t], Bh, acc,  0, 0, 0);
#pragma unroll
            for (int r = 0; r < 4; ++r) {
                const int i = t * 4 + r;
                const bool up = acc[r] > bval[i];   // strict '>': first tile
                bct[i]  = up ? ct : bct[i];         // v_cndmask (SGPR ct)
                bval[i] = fmaxf(bval[i], acc[r]);   // v_max_f32
            }
        }
        Bh = BhN; Bl = BlN;
    }

    // ---- tail: sequential LDS merge, rows of 17 u64 ----
    __syncthreads();                    // all waves done reading B
    u64* cand = reinterpret_cast<u64*>(lds);
    const int cbase = chunk * CCODES;
#pragma unroll
    for (int i = 0; i < 8; ++i) {
        const int t = i >> 2, r = i & 3;
        const int row = wave * 32 + t * 16 + 4 * g + r;
        const int idx = cbase + bct[i] * 16 + m;
        cand[row * 17 + m] = packVI(bval[i], idx);
    }
    __syncthreads();
    if (tid < PPB) {
        u64 bu = 0;
#pragma unroll
        for (int mm = 0; mm < 16; ++mm) {
            const u64 v = cand[tid * 17 + mm];
            if (v > bu) bu = v;
        }
        atomicMax(best + posBase0 + tid, bu);
    }
}

// Fallback (ws too small): scalar VALU scan, all 256 segments.
__global__ __launch_bounds__(256, 4) void vq_scalar(
    const float* __restrict__ z, const float* __restrict__ emb,
    u64* __restrict__ best)
{
    const int lin = blockIdx.x;           // 0..2047
    const int xcd = lin & 7, j = lin >> 3;
    const int seg    = xcd * 32 + (j & 31);
    const int posgrp = j >> 5;

    const int t  = posgrp * 256 + threadIdx.x;
    const int p0 = t, p1 = t + POS / 2;
    const int b0 = p0 >> 10, hw0 = p0 & (HWc - 1);
    const int b1 = p1 >> 10, hw1 = p1 & (HWc - 1);
    const float* zp0 = z + (size_t)b0 * Dc * HWc + hw0;
    const float* zp1 = z + (size_t)b1 * Dc * HWc + hw1;

    float za[Dc], zb[Dc];
#pragma unroll
    for (int d = 0; d < Dc; ++d) {
        za[d] = zp0[(size_t)d * HWc];
        zb[d] = zp1[(size_t)d * HWc];
    }
#pragma unroll
    for (int d = 0; d < Dc; ++d) asm volatile("" : "+v"(za[d]), "+v"(zb[d]));

    const int c0 = seg * 128;
    const float4* e4 = reinterpret_cast<const float4*>(emb + (size_t)c0 * Dc);
    float v0 = -INFINITY, v1 = -INFINITY;
    int   i0 = c0, i1 = c0;
#pragma unroll 1
    for (int cc = 0; cc < 128; ++cc, e4 += 8) {
        float a0 = 0.f, a1 = 0.f;
#pragma unroll
        for (int q = 0; q < 8; ++q) {
            const float4 e = e4[q];
            a0 = fmaf(za[4*q+0], e.x, a0); a1 = fmaf(zb[4*q+0], e.x, a1);
            a0 = fmaf(za[4*q+1], e.y, a0); a1 = fmaf(zb[4*q+1], e.y, a1);
            a0 = fmaf(za[4*q+2], e.z, a0); a1 = fmaf(zb[4*q+2], e.z, a1);
            a0 = fmaf(za[4*q+3], e.w, a0); a1 = fmaf(zb[4*q+3], e.w, a1);
        }
        const int c = c0 + cc;
        if (a0 > v0) { v0 = a0; i0 = c; }
        if (a1 > v1) { v1 = a1; i1 = c; }
    }
    atomicMax(best + p0, packVI(v0, i0));
    atomicMax(best + p1, packVI(v1, i1));
}

// Finish: decode winner, gather embedding row (float4, exact fp32 values),
// write z_q [b,d,h,w] coalesced, index as float (<=32767 exact in fp32).
__global__ __launch_bounds__(256) void vq_finish_kernel(
    const u64* __restrict__ best, const float* __restrict__ emb,
    float* __restrict__ zq, float* __restrict__ indOut)
{
    const int p = blockIdx.x * 256 + threadIdx.x;
    const u64 pk = best[p];
    const int idx = (int)(~(unsigned)pk);

    const float4* e = reinterpret_cast<const float4*>(emb + (size_t)idx * Dc);
    const int b  = p >> 10;
    const int hw = p & (HWc - 1);
    float* o = zq + (size_t)b * Dc * HWc + hw;
#pragma unroll
    for (int q = 0; q < 8; ++q) {
        const float4 v = e[q];
        o[(size_t)(4*q+0) * HWc] = v.x;
        o[(size_t)(4*q+1) * HWc] = v.y;
        o[(size_t)(4*q+2) * HWc] = v.z;
        o[(size_t)(4*q+3) * HWc] = v.w;
    }
    indOut[p] = (float)idx;
}

extern "C" void kernel_launch(void* const* d_in, const int* in_sizes, int n_in,
                              void* d_out, int out_size, void* d_ws, size_t ws_size,
                              hipStream_t stream)
{
    const float* z   = (const float*)d_in[0];
    const float* emb = (const float*)d_in[1];

    float* out    = (float*)d_out;
    float* zq     = out;                          // 131072 floats
    float* indOut = out + (size_t)Bc * Dc * HWc;  // 4096 index values (as f32)

    u64* best = (u64*)d_ws;                                      // 32 KB
    _Float16* Es = (_Float16*)((char*)d_ws + (size_t)POS * 8);   // 4 MB
    _Float16* Zs = Es + (size_t)NE * 64;                         // 512 KB
    const size_t needed = (size_t)POS * 8 + (size_t)(NE + POS) * 64 * 2;

    if (ws_size >= needed) {
        // eprep zeroes best[] -> no memset dispatch needed
        hipLaunchKernelGGL(vq_eprep, dim3(NE / 256 + POS / 256), dim3(256), 0,
                           stream, emb, z, Es, Zs, best);
        hipLaunchKernelGGL(vq_mfma, dim3(NCHUNK * NPBLK), dim3(256), 0, stream,
                           Zs, Es, best);
    } else {
        hipMemsetAsync(best, 0, (size_t)POS * sizeof(u64), stream);
        hipLaunchKernelGGL(vq_scalar, dim3(2048), dim3(256), 0, stream,
                           z, emb, best);
    }
    hipLaunchKernelGGL(vq_finish_kernel, dim3(POS / 256), dim3(256), 0, stream,
                       best, emb, zq, indOut);
}

// Round 14
// 46.425 us; speedup vs baseline: 1.0706x; 1.0706x over previous
//
#include <hip/hip_runtime.h>
#include <math.h>

// Problem constants: z [4,32,32,32] f32, embedding [32768,32] f32.
constexpr int Bc   = 4;
constexpr int Dc   = 32;
constexpr int HWc  = 1024;
constexpr int NE   = 32768;
constexpr int POS  = Bc * HWc;        // 4096 positions

constexpr int CCODES = 256;           // codes per block chunk (32 KB in LDS)
constexpr int NCHUNK = NE / CCODES;   // 128
constexpr int PPB    = 256;           // positions per block (8 waves x 32)
constexpr int NPBLK  = POS / PPB;     // 16

typedef _Float16 f16x8 __attribute__((ext_vector_type(8)));
typedef float    f32x4 __attribute__((ext_vector_type(4)));
typedef unsigned long long u64;

// Monotonic float->uint encoding; pack with ~idx so that among equal values
// the SMALLER index wins under max (== jnp.argmax first-index rule).
__device__ inline u64 packVI(float v, int idx) {
    unsigned u = __float_as_uint(v);
    u = (u & 0x80000000u) ? ~u : (u | 0x80000000u);
    return ((u64)u << 32) | (unsigned)(~idx);
}

// Prep: split-fp16 conversion. Blocks 0..127: embedding -> Es [32768][64]
// (hi dims 0..31, lo dims 32..63; hi+lo = x to ~2^-22). Blocks 128..143:
// z -> Zs [4096][64] same layout, and zero best[].
__global__ __launch_bounds__(256) void vq_eprep(
    const float* __restrict__ emb, const float* __restrict__ z,
    _Float16* __restrict__ Es, _Float16* __restrict__ Zs,
    u64* __restrict__ best)
{
    float x[Dc];
    _Float16* dptr;
    if (blockIdx.x < NE / 256) {
        const int c = blockIdx.x * 256 + threadIdx.x;       // 0..32767
        const float4* src = reinterpret_cast<const float4*>(emb + (size_t)c * Dc);
#pragma unroll
        for (int q = 0; q < 8; ++q) {
            const float4 v = src[q];
            x[4*q+0] = v.x; x[4*q+1] = v.y; x[4*q+2] = v.z; x[4*q+3] = v.w;
        }
        dptr = Es + (size_t)c * 64;
    } else {
        const int p = (blockIdx.x - NE / 256) * 256 + threadIdx.x;  // 0..4095
        best[p] = 0ULL;            // encoded minimum: any real value wins
        const int b = p >> 10, hw = p & (HWc - 1);
        const float* zp = z + (size_t)b * Dc * HWc + hw;
#pragma unroll
        for (int d = 0; d < Dc; ++d) x[d] = zp[(size_t)d * HWc];
        dptr = Zs + (size_t)p * 64;
    }
    f16x8* dst = reinterpret_cast<f16x8*>(dptr);
#pragma unroll
    for (int q = 0; q < 4; ++q) {
        f16x8 h, l;
#pragma unroll
        for (int r = 0; r < 8; ++r) {
            const float xv = x[8*q+r];
            const _Float16 hv = (_Float16)xv;
            h[r] = hv;
            l[r] = (_Float16)(xv - (float)hv);
        }
        dst[q]     = h;   // hi block
        dst[4 + q] = l;   // lo block
    }
}

// Main: validated split-fp16 MFMA scan (hi*hi + hi*lo + lo*hi; absmax 0
// since round 8). Round-14: occupancy at last. r10-r13 all allocated ~176-224
// VGPR (2.5 waves/SIMD; per-wave VALU duty only ~24% -- latency-bound).
// (1) amdgpu_waves_per_eu(4,8): the backend attribute that actually sets the
//     VGPR budget to 512/4 = 128 (launch_bounds' cap was not honored).
// (2) 8 waves/block, 2048 blocks: staging instrs, barriers, tail amortized
//     2x better per position; same total wave count.
// (3) Natural live state ~80 regs (A 16, B 16, track 16, zacc 4) -> the 128
//     cap should not spill. Staging/read swizzle identical to r10 (0 confl).
__global__ __launch_bounds__(512)
__attribute__((amdgpu_waves_per_eu(4, 8)))
void vq_mfma(
    const _Float16* __restrict__ Zs, const _Float16* __restrict__ Es,
    u64* __restrict__ best)
{
    __shared__ __align__(16) char lds[PPB * 17 * 8];   // 34816 B (tail needs most)

    const int lin  = blockIdx.x;               // 0..2047
    const int xcd  = lin & 7;                  // dispatch round-robins XCDs
    const int j    = lin >> 3;                 // 0..255
    const int chunk = xcd * (NCHUNK / 8) + (j & (NCHUNK / 8 - 1));
    const int pblk  = j >> 4;                  // 0..15
    const int tid  = threadIdx.x;
    const int wave = tid >> 6, lane = tid & 63;
    const int m = lane & 15, g = lane >> 4;

    // ---- stage chunk -> LDS via global_load_lds, source pre-swizzled ----
    // LDS[row][col16B] = src[row][col ^ (row&7)] (XOR involution), 4 passes.
    {
        const char* src = (const char*)(Es + (size_t)chunk * CCODES * 64);
        char* dstbase = lds + wave * 1024;           // wave-uniform base
#pragma unroll
        for (int r = 0; r < 4; ++r) {
            const int o    = r * 512 + tid;          // 16B-chunk index 0..2047
            const int row  = o >> 3;                 // code row 0..255
            const int ccol = o & 7;                  // 16B col 0..7
            const int soff = row * 128 + ((ccol ^ (row & 7)) << 4);
            __builtin_amdgcn_global_load_lds(
                (const __attribute__((address_space(1))) void*)(src + soff),
                (__attribute__((address_space(3))) void*)(dstbase + r * 8192),
                16, 0, 0);
        }
    }

    // ---- A fragments: 2 pos-tiles, plain 16B loads from preconverted Zs ----
    const int posBase0 = pblk * PPB;
    const int posBase  = posBase0 + wave * 32;
    f16x8 Ahi[2], Alo[2];
#pragma unroll
    for (int t = 0; t < 2; ++t) {
        const _Float16* zrow = Zs + (size_t)(posBase + t * 16 + m) * 64 + 8 * g;
        Ahi[t] = *reinterpret_cast<const f16x8*>(zrow);
        Alo[t] = *reinterpret_cast<const f16x8*>(zrow + 32);
    }
#pragma unroll
    for (int t = 0; t < 2; ++t) asm volatile("" : "+v"(Ahi[t]), "+v"(Alo[t]));

    f32x4 zacc = {0.f, 0.f, 0.f, 0.f};
    asm volatile("" : "+v"(zacc));     // persistent zero C-operand quad

    float bval[8];
    int   bct[8];
#pragma unroll
    for (int i = 0; i < 8; ++i) { bval[i] = -INFINITY; bct[i] = 0; }

    __syncthreads();   // staging complete

    // ---- hot loop: 16 code-tiles from LDS ----
    const char* lbase = lds;
    const int off_h = m * 128 + (( g      ^ (m & 7)) << 4);
    const int off_l = m * 128 + (((g + 4) ^ (m & 7)) << 4);

#pragma unroll 2
    for (int ct = 0; ct < CCODES / 16; ++ct) {
        const f16x8 Bh = *reinterpret_cast<const f16x8*>(lbase + off_h + ct * 2048);
        const f16x8 Bl = *reinterpret_cast<const f16x8*>(lbase + off_l + ct * 2048);

#pragma unroll
        for (int t = 0; t < 2; ++t) {
            f32x4 acc;
            acc = __builtin_amdgcn_mfma_f32_16x16x32_f16(Ahi[t], Bh, zacc, 0, 0, 0);
            acc = __builtin_amdgcn_mfma_f32_16x16x32_f16(Ahi[t], Bl, acc,  0, 0, 0);
            acc = __builtin_amdgcn_mfma_f32_16x16x32_f16(Alo[t], Bh, acc,  0, 0, 0);
#pragma unroll
            for (int r = 0; r < 4; ++r) {
                const int i = t * 4 + r;
                const bool up = acc[r] > bval[i];   // strict '>': first tile
                bct[i]  = up ? ct : bct[i];         // v_cndmask (SGPR ct)
                bval[i] = fmaxf(bval[i], acc[r]);   // v_max_f32
            }
        }
    }

    // ---- tail: LDS merge, rows of 17 u64 (bank varies with row) ----
    __syncthreads();                    // all waves done reading B
    u64* cand = reinterpret_cast<u64*>(lds);
    const int cbase = chunk * CCODES;
#pragma unroll
    for (int i = 0; i < 8; ++i) {
        const int t = i >> 2, r = i & 3;
        const int row = wave * 32 + t * 16 + 4 * g + r;
        const int idx = cbase + bct[i] * 16 + m;
        cand[row * 17 + m] = packVI(bval[i], idx);
    }
    __syncthreads();
    if (tid < PPB) {
        u64 bu = 0;
#pragma unroll
        for (int mm = 0; mm < 16; ++mm) {
            const u64 v = cand[tid * 17 + mm];
            if (v > bu) bu = v;
        }
        atomicMax(best + posBase0 + tid, bu);
    }
}

// Fallback (ws too small): scalar VALU scan, all 256 segments.
__global__ __launch_bounds__(256, 4) void vq_scalar(
    const float* __restrict__ z, const float* __restrict__ emb,
    u64* __restrict__ best)
{
    const int lin = blockIdx.x;           // 0..2047
    const int xcd = lin & 7, j = lin >> 3;
    const int seg    = xcd * 32 + (j & 31);
    const int posgrp = j >> 5;

    const int t  = posgrp * 256 + threadIdx.x;
    const int p0 = t, p1 = t + POS / 2;
    const int b0 = p0 >> 10, hw0 = p0 & (HWc - 1);
    const int b1 = p1 >> 10, hw1 = p1 & (HWc - 1);
    const float* zp0 = z + (size_t)b0 * Dc * HWc + hw0;
    const float* zp1 = z + (size_t)b1 * Dc * HWc + hw1;

    float za[Dc], zb[Dc];
#pragma unroll
    for (int d = 0; d < Dc; ++d) {
        za[d] = zp0[(size_t)d * HWc];
        zb[d] = zp1[(size_t)d * HWc];
    }
#pragma unroll
    for (int d = 0; d < Dc; ++d) asm volatile("" : "+v"(za[d]), "+v"(zb[d]));

    const int c0 = seg * 128;
    const float4* e4 = reinterpret_cast<const float4*>(emb + (size_t)c0 * Dc);
    float v0 = -INFINITY, v1 = -INFINITY;
    int   i0 = c0, i1 = c0;
#pragma unroll 1
    for (int cc = 0; cc < 128; ++cc, e4 += 8) {
        float a0 = 0.f, a1 = 0.f;
#pragma unroll
        for (int q = 0; q < 8; ++q) {
            const float4 e = e4[q];
            a0 = fmaf(za[4*q+0], e.x, a0); a1 = fmaf(zb[4*q+0], e.x, a1);
            a0 = fmaf(za[4*q+1], e.y, a0); a1 = fmaf(zb[4*q+1], e.y, a1);
            a0 = fmaf(za[4*q+2], e.z, a0); a1 = fmaf(zb[4*q+2], e.z, a1);
            a0 = fmaf(za[4*q+3], e.w, a0); a1 = fmaf(zb[4*q+3], e.w, a1);
        }
        const int c = c0 + cc;
        if (a0 > v0) { v0 = a0; i0 = c; }
        if (a1 > v1) { v1 = a1; i1 = c; }
    }
    atomicMax(best + p0, packVI(v0, i0));
    atomicMax(best + p1, packVI(v1, i1));
}

// Finish: decode winner, gather embedding row (float4, exact fp32 values),
// write z_q [b,d,h,w] coalesced, index as float (<=32767 exact in fp32).
__global__ __launch_bounds__(256) void vq_finish_kernel(
    const u64* __restrict__ best, const float* __restrict__ emb,
    float* __restrict__ zq, float* __restrict__ indOut)
{
    const int p = blockIdx.x * 256 + threadIdx.x;
    const u64 pk = best[p];
    const int idx = (int)(~(unsigned)pk);

    const float4* e = reinterpret_cast<const float4*>(emb + (size_t)idx * Dc);
    const int b  = p >> 10;
    const int hw = p & (HWc - 1);
    float* o = zq + (size_t)b * Dc * HWc + hw;
#pragma unroll
    for (int q = 0; q < 8; ++q) {
        const float4 v = e[q];
        o[(size_t)(4*q+0) * HWc] = v.x;
        o[(size_t)(4*q+1) * HWc] = v.y;
        o[(size_t)(4*q+2) * HWc] = v.z;
        o[(size_t)(4*q+3) * HWc] = v.w;
    }
    indOut[p] = (float)idx;
}

extern "C" void kernel_launch(void* const* d_in, const int* in_sizes, int n_in,
                              void* d_out, int out_size, void* d_ws, size_t ws_size,
                              hipStream_t stream)
{
    const float* z   = (const float*)d_in[0];
    const float* emb = (const float*)d_in[1];

    float* out    = (float*)d_out;
    float* zq     = out;                          // 131072 floats
    float* indOut = out + (size_t)Bc * Dc * HWc;  // 4096 index values (as f32)

    u64* best = (u64*)d_ws;                                      // 32 KB
    _Float16* Es = (_Float16*)((char*)d_ws + (size_t)POS * 8);   // 4 MB
    _Float16* Zs = Es + (size_t)NE * 64;                         // 512 KB
    const size_t needed = (size_t)POS * 8 + (size_t)(NE + POS) * 64 * 2;

    if (ws_size >= needed) {
        // eprep zeroes best[] -> no memset dispatch needed
        hipLaunchKernelGGL(vq_eprep, dim3(NE / 256 + POS / 256), dim3(256), 0,
                           stream, emb, z, Es, Zs, best);
        hipLaunchKernelGGL(vq_mfma, dim3(NCHUNK * NPBLK), dim3(512), 0, stream,
                           Zs, Es, best);
    } else {
        hipMemsetAsync(best, 0, (size_t)POS * sizeof(u64), stream);
        hipLaunchKernelGGL(vq_scalar, dim3(2048), dim3(256), 0, stream,
                           z, emb, best);
    }
    hipLaunchKernelGGL(vq_finish_kernel, dim3(POS / 256), dim3(256), 0, stream,
                       best, emb, zq, indOut);
}